// Round 5
// baseline (114.732 us; speedup 1.0000x reference)
//
#include <hip/hip_runtime.h>
#include <hip/hip_bf16.h>
#include <math.h>

typedef __attribute__((ext_vector_type(8))) short short8;
typedef __attribute__((ext_vector_type(4))) float f32x4;
typedef __attribute__((ext_vector_type(4))) unsigned short u16x4;
typedef unsigned int u32;
typedef unsigned short u16;

#define DDIM 512
#define KCL 64
#define NPOS 4096
#define NSPL 8
#define EPSF 1e-12f

__device__ __forceinline__ u16 f2bf(float x) {
    __hip_bfloat16 h = __float2bfloat16(x);
    return __builtin_bit_cast(u16, h);
}
__device__ __forceinline__ float bf2f(u16 u) {
    unsigned i = ((unsigned)u) << 16;
    return __builtin_bit_cast(float, i);
}

// ---------------------------------------------------------------------------
// scores = softmax_k(W @ desc + b) -> P packed u32 (bf16 hi | lo<<16) [B][K][N]
// grid (32 nblk, B), 256 thr = 4 waves x (64k x 32n). Split-bf16: hh+lh+hl.
// B-operand via R2-proven scalar LDS gather from [d][n] tiles (pitch 130).
__global__ __launch_bounds__(256) void k_scores(const float* __restrict__ desc,
        const float* __restrict__ W, const float* __restrict__ bias,
        u32* __restrict__ P, float* __restrict__ pssum) {
    const int nblk = blockIdx.x, b = blockIdx.y;
    const int t = threadIdx.x;
    const int w = t >> 6, lane = t & 63, c = lane & 15, g = lane >> 4;

    __shared__ u16 Wh[64][72], Wl[64][72];     // [k][d] pitch 72
    __shared__ u16 Dh[64][130], Dl[64][130];   // [d][n] pitch 130

    f32x4 acc[4][2];
#pragma unroll
    for (int mf = 0; mf < 4; ++mf)
#pragma unroll
        for (int nf = 0; nf < 2; ++nf) acc[mf][nf] = (f32x4){0.f, 0.f, 0.f, 0.f};

    f32x4 bv[4];
#pragma unroll
    for (int mf = 0; mf < 4; ++mf) bv[mf] = *(const f32x4*)&bias[mf * 16 + g * 4];

    const int rl = t >> 2, q = t & 3;

    for (int dt = 0; dt < 8; ++dt) {
        const int d0 = dt * 64;
        // stage W tile [64k][64d] -> hi/lo bf16
#pragma unroll
        for (int u = 0; u < 4; ++u) {
            const int dd = u * 16 + q * 4;
            float4 wv = *(const float4*)&W[(size_t)rl * DDIM + d0 + dd];
            u16 h0 = f2bf(wv.x), h1 = f2bf(wv.y), h2 = f2bf(wv.z), h3 = f2bf(wv.w);
            *(u16x4*)&Wh[rl][dd] = (u16x4){h0, h1, h2, h3};
            *(u16x4*)&Wl[rl][dd] = (u16x4){f2bf(wv.x - bf2f(h0)), f2bf(wv.y - bf2f(h1)),
                                           f2bf(wv.z - bf2f(h2)), f2bf(wv.w - bf2f(h3))};
        }
        // stage desc tile [64d][128n] -> hi/lo bf16
        {
            const float* dsrc = desc + ((size_t)b * DDIM + d0 + rl) * NPOS + nblk * 128;
#pragma unroll
            for (int u = 0; u < 8; ++u) {
                const int n = u * 16 + q * 4;
                float4 dv = *(const float4*)&dsrc[n];
                u16 h0 = f2bf(dv.x), h1 = f2bf(dv.y), h2 = f2bf(dv.z), h3 = f2bf(dv.w);
                *(u16x4*)&Dh[rl][n] = (u16x4){h0, h1, h2, h3};
                *(u16x4*)&Dl[rl][n] =
                    (u16x4){f2bf(dv.x - bf2f(h0)), f2bf(dv.y - bf2f(h1)),
                            f2bf(dv.z - bf2f(h2)), f2bf(dv.w - bf2f(h3))};
            }
        }
        __syncthreads();
#pragma unroll
        for (int ks = 0; ks < 2; ++ks) {
            const int kk = ks * 32 + g * 8;
#pragma unroll
            for (int nf = 0; nf < 2; ++nf) {
                const int nc = w * 32 + nf * 16 + c;
                short8 bh, bl;
#pragma unroll
                for (int j = 0; j < 8; ++j) {
                    bh[j] = (short)Dh[kk + j][nc];
                    bl[j] = (short)Dl[kk + j][nc];
                }
#pragma unroll
                for (int mf = 0; mf < 4; ++mf) {
                    short8 ah = *(const short8*)&Wh[mf * 16 + c][kk];
                    short8 al = *(const short8*)&Wl[mf * 16 + c][kk];
                    acc[mf][nf] = __builtin_amdgcn_mfma_f32_16x16x32_bf16(ah, bh, acc[mf][nf], 0, 0, 0);
                    acc[mf][nf] = __builtin_amdgcn_mfma_f32_16x16x32_bf16(al, bh, acc[mf][nf], 0, 0, 0);
                    acc[mf][nf] = __builtin_amdgcn_mfma_f32_16x16x32_bf16(ah, bl, acc[mf][nf], 0, 0, 0);
                }
            }
        }
        __syncthreads();
    }

    // epilogue: +bias, softmax over 64 k, pack+store P, ssum partials
#pragma unroll
    for (int mf = 0; mf < 4; ++mf)
#pragma unroll
        for (int nf = 0; nf < 2; ++nf) acc[mf][nf] = acc[mf][nf] + bv[mf];

    float ps[4][4];
#pragma unroll
    for (int mf = 0; mf < 4; ++mf)
#pragma unroll
        for (int r = 0; r < 4; ++r) ps[mf][r] = 0.f;

#pragma unroll
    for (int nf = 0; nf < 2; ++nf) {
        float m = acc[0][nf][0];
#pragma unroll
        for (int mf = 0; mf < 4; ++mf)
#pragma unroll
            for (int r = 0; r < 4; ++r) m = fmaxf(m, acc[mf][nf][r]);
        m = fmaxf(m, __shfl_xor(m, 16));
        m = fmaxf(m, __shfl_xor(m, 32));
        float s = 0.f;
#pragma unroll
        for (int mf = 0; mf < 4; ++mf)
#pragma unroll
            for (int r = 0; r < 4; ++r) {
                float p = __expf(acc[mf][nf][r] - m);
                acc[mf][nf][r] = p;
                s += p;
            }
        s += __shfl_xor(s, 16);
        s += __shfl_xor(s, 32);
        const float inv = 1.0f / s;
        const int n = nblk * 128 + w * 32 + nf * 16 + c;
#pragma unroll
        for (int mf = 0; mf < 4; ++mf) {
#pragma unroll
            for (int r = 0; r < 4; ++r) {
                float p = acc[mf][nf][r] * inv;
                ps[mf][r] += p;
                u16 h = f2bf(p);
                u16 l = f2bf(p - bf2f(h));
                u32 pk = (u32)h | ((u32)l << 16);
                const int k = mf * 16 + g * 4 + r;
                P[((size_t)b * KCL + k) * NPOS + n] = pk;
            }
        }
    }
#pragma unroll
    for (int mf = 0; mf < 4; ++mf)
#pragma unroll
        for (int r = 0; r < 4; ++r) {
            float v = ps[mf][r];
            v += __shfl_xor(v, 1);
            v += __shfl_xor(v, 2);
            v += __shfl_xor(v, 4);
            v += __shfl_xor(v, 8);
            ps[mf][r] = v;
        }
    if (c == 0) {
#pragma unroll
        for (int mf = 0; mf < 4; ++mf) {
            float4 o = make_float4(ps[mf][0], ps[mf][1], ps[mf][2], ps[mf][3]);
            *(float4*)&pssum[((size_t)b * 128 + nblk * 4 + w) * KCL + mf * 16 + g * 4] = o;
        }
    }
}

// ---------------------------------------------------------------------------
// part[ns][b][k][d] = sum_{n in slice} desc[b][d][n] * P[b][n][k]
// grid (4 dblk, 8 ns, B), 256 thr = 4 waves (wm,wk); block tile [128d][64k].
// A = desc split-bf16 (rows along n), B = P packed rows along n: no transpose.
__global__ __launch_bounds__(256) void k_agg(const float* __restrict__ desc,
        const u32* __restrict__ P, float* __restrict__ part, int B) {
    const int dblk = blockIdx.x, ns = blockIdx.y, b = blockIdx.z;
    const int t = threadIdx.x;
    const int w = t >> 6, lane = t & 63, c = lane & 15, g = lane >> 4;
    const int wm = w & 1, wk = w >> 1;

    __shared__ u16 Ahs[128][72], Als[128][72];  // desc bf16 [d][n] pitch 72
    __shared__ u32 Pt[64][68];                  // P packed [k][n] pitch 68

    f32x4 acc[4][2];
#pragma unroll
    for (int mf = 0; mf < 4; ++mf)
#pragma unroll
        for (int nf = 0; nf < 2; ++nf) acc[mf][nf] = (f32x4){0.f, 0.f, 0.f, 0.f};

    const int rl = t >> 2, q = t & 3;

    for (int nt = 0; nt < 8; ++nt) {
        const int n0 = ns * 512 + nt * 64;
        // A: desc [128d][64n] -> hi/lo bf16
#pragma unroll
        for (int rr = 0; rr < 2; ++rr) {
            const int row = rr * 64 + rl;
            const float* s = desc + ((size_t)b * DDIM + dblk * 128 + row) * NPOS + n0;
#pragma unroll
            for (int u = 0; u < 4; ++u) {
                const int n = u * 16 + q * 4;
                float4 dv = *(const float4*)&s[n];
                u16 h0 = f2bf(dv.x), h1 = f2bf(dv.y), h2 = f2bf(dv.z), h3 = f2bf(dv.w);
                *(u16x4*)&Ahs[row][n] = (u16x4){h0, h1, h2, h3};
                *(u16x4*)&Als[row][n] =
                    (u16x4){f2bf(dv.x - bf2f(h0)), f2bf(dv.y - bf2f(h1)),
                            f2bf(dv.z - bf2f(h2)), f2bf(dv.w - bf2f(h3))};
            }
        }
        // B: P [64k][64n] packed u32, b128 loads
        {
            const u32* pr = P + ((size_t)b * KCL + rl) * NPOS + n0;
#pragma unroll
            for (int u = 0; u < 4; ++u) {
                const int n = u * 16 + q * 4;
                *(uint4*)&Pt[rl][n] = *(const uint4*)&pr[n];
            }
        }
        __syncthreads();
#pragma unroll
        for (int ks = 0; ks < 2; ++ks) {
            const int kk = ks * 32 + g * 8;
            short8 ah[4], al[4];
#pragma unroll
            for (int mf = 0; mf < 4; ++mf) {
                ah[mf] = *(const short8*)&Ahs[wm * 64 + mf * 16 + c][kk];
                al[mf] = *(const short8*)&Als[wm * 64 + mf * 16 + c][kk];
            }
#pragma unroll
            for (int nf = 0; nf < 2; ++nf) {
                const u32* pr = &Pt[wk * 32 + nf * 16 + c][kk];
                uint4 x01 = *(const uint4*)&pr[0];
                uint4 x23 = *(const uint4*)&pr[4];
                uint4 H, L;
                H.x = (x01.x & 0xffffu) | (x01.y << 16);
                L.x = (x01.x >> 16) | (x01.y & 0xffff0000u);
                H.y = (x01.z & 0xffffu) | (x01.w << 16);
                L.y = (x01.z >> 16) | (x01.w & 0xffff0000u);
                H.z = (x23.x & 0xffffu) | (x23.y << 16);
                L.z = (x23.x >> 16) | (x23.y & 0xffff0000u);
                H.w = (x23.z & 0xffffu) | (x23.w << 16);
                L.w = (x23.z >> 16) | (x23.w & 0xffff0000u);
                short8 bh = __builtin_bit_cast(short8, H);
                short8 bl = __builtin_bit_cast(short8, L);
#pragma unroll
                for (int mf = 0; mf < 4; ++mf) {
                    acc[mf][nf] = __builtin_amdgcn_mfma_f32_16x16x32_bf16(ah[mf], bh, acc[mf][nf], 0, 0, 0);
                    acc[mf][nf] = __builtin_amdgcn_mfma_f32_16x16x32_bf16(al[mf], bh, acc[mf][nf], 0, 0, 0);
                    acc[mf][nf] = __builtin_amdgcn_mfma_f32_16x16x32_bf16(ah[mf], bl, acc[mf][nf], 0, 0, 0);
                }
            }
        }
        __syncthreads();
    }
    // C[row=d][col=k] -> part[ns][b][k][d], float4 per (mf,nf)
#pragma unroll
    for (int nf = 0; nf < 2; ++nf) {
        const int k = wk * 32 + nf * 16 + c;
#pragma unroll
        for (int mf = 0; mf < 4; ++mf) {
            float4 o = make_float4(acc[mf][nf][0], acc[mf][nf][1], acc[mf][nf][2], acc[mf][nf][3]);
            *(float4*)&part[(((size_t)ns * B + b) * KCL + k) * DDIM + dblk * 128 + wm * 64 + mf * 16 + g * 4] = o;
        }
    }
}

// ---------------------------------------------------------------------------
__global__ __launch_bounds__(256) void k_reduce(const float* __restrict__ part,
                                                float* __restrict__ agg, int bkd) {
    size_t e = ((size_t)blockIdx.x * 256 + threadIdx.x) * 4;
    if (e >= (size_t)bkd) return;
    float4 a = *(const float4*)&part[e];
#pragma unroll
    for (int s = 1; s < NSPL; ++s) {
        float4 v = *(const float4*)&part[(size_t)s * bkd + e];
        a.x += v.x; a.y += v.y; a.z += v.z; a.w += v.w;
    }
    *(float4*)&agg[e] = a;
}

// centersT[k][d] <- centers[d][k]
__global__ __launch_bounds__(256) void k_centersT(const float* __restrict__ cen,
                                                  float* __restrict__ cT) {
    __shared__ float Lx[64][65];
    const int dc = blockIdx.x, t = threadIdx.x, r = t >> 2, q = t & 3;
#pragma unroll
    for (int u = 0; u < 4; ++u) {
        const int k = q * 16 + u * 4;
        float4 v = *(const float4*)&cen[((size_t)dc * 64 + r) * KCL + k];
        Lx[r][k] = v.x; Lx[r][k + 1] = v.y; Lx[r][k + 2] = v.z; Lx[r][k + 3] = v.w;
    }
    __syncthreads();
#pragma unroll
    for (int u = 0; u < 4; ++u) {
        const int d = q * 16 + u * 4;
        float4 o = make_float4(Lx[d][r], Lx[d + 1][r], Lx[d + 2][r], Lx[d + 3][r]);
        *(float4*)&cT[(size_t)r * DDIM + dc * 64 + d] = o;
    }
}

__global__ void k_mid(const float* __restrict__ pssum, float* __restrict__ ssum) {
    const int b = blockIdx.x, k = threadIdx.x;
    float a = 0.f;
    for (int nw = 0; nw < 128; ++nw) a += pssum[((size_t)b * 128 + nw) * KCL + k];
    ssum[b * KCL + k] = a;
}

// per-(b,k) column norms on v = agg - cT*ssum; invc = 1/(gn * clamp(cn))
__global__ __launch_bounds__(256) void k_norms(const float* __restrict__ agg,
        const float* __restrict__ cT, const float* __restrict__ ssum,
        float* __restrict__ invc) {
    const int b = blockIdx.x, t = threadIdx.x, w = t >> 6, lane = t & 63;
    __shared__ float cc[64], gp[4];
    float gacc = 0.f;
    for (int i = 0; i < 16; ++i) {
        const int k = w * 16 + i;
        const float sm = ssum[b * KCL + k];
        const float* ar = agg + ((size_t)b * KCL + k) * DDIM + lane * 8;
        const float* cr = cT + (size_t)k * DDIM + lane * 8;
        float sq = 0.f;
#pragma unroll
        for (int j = 0; j < 8; ++j) {
            float v = fmaf(-cr[j], sm, ar[j]);
            sq = fmaf(v, v, sq);
        }
#pragma unroll
        for (int off = 32; off >= 1; off >>= 1) sq += __shfl_xor(sq, off);
        float cl = fmaxf(sqrtf(sq), EPSF);
        if (lane == 0) cc[k] = cl;
        gacc += sq / (cl * cl);
    }
    if (lane == 0) gp[w] = gacc;
    __syncthreads();
    if (t < 64) {
        float gn = fmaxf(sqrtf(gp[0] + gp[1] + gp[2] + gp[3]), EPSF);
        invc[b * KCL + t] = 1.0f / (gn * cc[t]);
    }
}

// out[b][d][k] = (agg[b][k][d] - cT[k][d]*ssum) * invc[b][k]  (LDS transpose)
__global__ __launch_bounds__(256) void k_out(const float* __restrict__ agg,
        const float* __restrict__ cT, const float* __restrict__ ssum,
        const float* __restrict__ invc, float* __restrict__ out) {
    const int dc = blockIdx.x, b = blockIdx.y;
    const int t = threadIdx.x, r = t >> 2, q = t & 3;
    __shared__ float Lx[64][65];
    const float sm = ssum[b * KCL + r], ic = invc[b * KCL + r];
#pragma unroll
    for (int u = 0; u < 4; ++u) {
        const int d = q * 16 + u * 4;
        float4 a = *(const float4*)&agg[((size_t)b * KCL + r) * DDIM + dc * 64 + d];
        float4 cv = *(const float4*)&cT[(size_t)r * DDIM + dc * 64 + d];
        Lx[r][d]     = fmaf(-cv.x, sm, a.x) * ic;
        Lx[r][d + 1] = fmaf(-cv.y, sm, a.y) * ic;
        Lx[r][d + 2] = fmaf(-cv.z, sm, a.z) * ic;
        Lx[r][d + 3] = fmaf(-cv.w, sm, a.w) * ic;
    }
    __syncthreads();
#pragma unroll
    for (int u = 0; u < 4; ++u) {
        const int k = q * 16 + u * 4;
        float4 o = make_float4(Lx[k][r], Lx[k + 1][r], Lx[k + 2][r], Lx[k + 3][r]);
        *(float4*)&out[((size_t)b * DDIM + dc * 64 + r) * KCL + k] = o;
    }
}

// ---------------------------------------------------------------------------
extern "C" void kernel_launch(void* const* d_in, const int* in_sizes, int n_in,
                              void* d_out, int out_size, void* d_ws, size_t ws_size,
                              hipStream_t stream) {
    const float* desc    = (const float*)d_in[0];
    const float* W       = (const float*)d_in[1];
    const float* bias    = (const float*)d_in[2];
    const float* centers = (const float*)d_in[3];
    float* out = (float*)d_out;

    const int B = in_sizes[0] / (DDIM * NPOS);  // 16

    char* ws = (char*)d_ws;
    const size_t pSz    = (size_t)B * KCL * NPOS * 4;        // 16.78 MB (packed u32)
    const size_t partSz = (size_t)NSPL * B * KCL * DDIM * 4; // 16.78 MB
    u32*   P     = (u32*)ws;
    float* part  = (float*)(ws + pSz);
    float* pssum = part;  // aliased: consumed by k_mid before k_agg writes part
    float* agg   = (float*)(ws + pSz + partSz);
    float* cT    = agg + (size_t)B * KCL * DDIM;
    float* ssum  = cT + (size_t)KCL * DDIM;
    float* invc  = ssum + B * KCL;

    k_centersT<<<8, 256, 0, stream>>>(centers, cT);
    k_scores<<<dim3(NPOS / 128, B), 256, 0, stream>>>(desc, W, bias, P, pssum);
    k_mid<<<B, 64, 0, stream>>>(pssum, ssum);
    k_agg<<<dim3(4, NSPL, B), 256, 0, stream>>>(desc, P, part, B);
    k_reduce<<<(B * KCL * DDIM) / 1024, 256, 0, stream>>>(part, agg, B * KCL * DDIM);
    k_norms<<<B, 256, 0, stream>>>(agg, cT, ssum, invc);
    k_out<<<dim3(8, B), 256, 0, stream>>>(agg, cT, ssum, invc, out);
}